// Round 6
// baseline (10204.244 us; speedup 1.0000x reference)
//
#include <hip/hip_runtime.h>
#include <cfloat>

#define DIM_IN 256
#define HIDDEN 32
#define NE 64
#define ECH 16
#define BLOCK 256
#define OPAD 20  // obuf row stride (floats): 16B-aligned, 2-way banks (free)

typedef float f32x4 __attribute__((ext_vector_type(4)));

// One token per thread (VGPR ~90 < 128 cap: no spill — round-5 lesson).
// x is software-pipelined: double-buffered 64B register groups, nontemporal
// loads (zero-reuse stream; keep W1/W2 resident in L2 for the scalar pipe).
// Weights read with wave-uniform indices -> s_load on the scalar pipe.
// Output goes through a padded LDS transpose -> full-64B-line float4 stores.
__launch_bounds__(BLOCK, 4)
__global__ void router_fwd(const float* __restrict__ x,
                           const float* __restrict__ W1,
                           const float* __restrict__ b1,
                           const float* __restrict__ W2,
                           const float* __restrict__ b2,
                           float* __restrict__ out, int n) {
  __shared__ float obuf[BLOCK][OPAD];
  const int tid = threadIdx.x;
  const long t = (long)blockIdx.x * BLOCK + tid;
  const bool av = t < n;

  const f32x4* __restrict__ xr =
      reinterpret_cast<const f32x4*>(x + (av ? t : 0) * DIM_IN);

  float h[HIDDEN];
#pragma unroll
  for (int j = 0; j < HIDDEN; ++j) h[j] = 0.0f;

  // 16 rows of W1 against 16 x-values (64B), fully unrolled inside.
  auto fma16 = [&](int g, const f32x4 q0, const f32x4 q1,
                   const f32x4 q2, const f32x4 q3) {
    const float xs[16] = {q0.x, q0.y, q0.z, q0.w, q1.x, q1.y, q1.z, q1.w,
                          q2.x, q2.y, q2.z, q2.w, q3.x, q3.y, q3.z, q3.w};
    const float* __restrict__ wbase = W1 + g * 16 * HIDDEN;  // uniform
#pragma unroll
    for (int k = 0; k < 16; ++k) {
      const float xv = xs[k];
      const float* __restrict__ wrow = wbase + k * HIDDEN;
#pragma unroll
      for (int j = 0; j < HIDDEN; ++j) h[j] = fmaf(xv, wrow[j], h[j]);
    }
  };

  // ---- layer 1: h = x @ W1, double-buffered A/B prefetch pipeline ----
  f32x4 A0 = __builtin_nontemporal_load(xr + 0);
  f32x4 A1 = __builtin_nontemporal_load(xr + 1);
  f32x4 A2 = __builtin_nontemporal_load(xr + 2);
  f32x4 A3 = __builtin_nontemporal_load(xr + 3);

#pragma unroll 1
  for (int g = 0; g < 16; g += 2) {
    const int pb = (g + 1) * 4;
    const f32x4 B0 = __builtin_nontemporal_load(xr + pb + 0);
    const f32x4 B1 = __builtin_nontemporal_load(xr + pb + 1);
    const f32x4 B2 = __builtin_nontemporal_load(xr + pb + 2);
    const f32x4 B3 = __builtin_nontemporal_load(xr + pb + 3);
    fma16(g, A0, A1, A2, A3);
    const int pa = ((g + 2) & 15) * 4;  // last iter: wrapped reload (unused)
    A0 = __builtin_nontemporal_load(xr + pa + 0);
    A1 = __builtin_nontemporal_load(xr + pa + 1);
    A2 = __builtin_nontemporal_load(xr + pa + 2);
    A3 = __builtin_nontemporal_load(xr + pa + 3);
    fma16(g + 1, B0, B1, B2, B3);
  }

  // bias + tanh.  tanh(v) = 1 - 2/(e^{2v}+1): no inf/inf NaN.
#pragma unroll
  for (int j = 0; j < HIDDEN; ++j) {
    const float v = h[j] + b1[j];
    const float e = __expf(2.0f * v);
    h[j] = 1.0f - 2.0f / (e + 1.0f);
  }

  // ---- layer 2 in 16-expert chunks + online top-2 / exp-sum ----
  float v1 = -FLT_MAX, v2 = -FLT_MAX, S = 0.0f;
  int i1 = 0, i2 = 0;

#pragma unroll 1
  for (int c = 0; c < NE / ECH; ++c) {
    float zc[ECH];
#pragma unroll
    for (int e = 0; e < ECH; ++e) zc[e] = 0.0f;
#pragma unroll
    for (int j = 0; j < HIDDEN; ++j) {
      const float hv = h[j];
      const float* __restrict__ wrow = W2 + j * NE + c * ECH;  // uniform
#pragma unroll
      for (int e = 0; e < ECH; ++e) zc[e] = fmaf(hv, wrow[e], zc[e]);
    }
    const float m_prev = v1;
    // strict '>' ascending scan => ties pick lower index (lax.top_k)
#pragma unroll
    for (int e = 0; e < ECH; ++e) {
      const float v = (zc[e] + b2[c * ECH + e]) * 10.0f;  // /TEMP
      zc[e] = v;
      const int ge = c * ECH + e;
      const bool g1 = v > v1;
      const bool g2 = v > v2;
      v2 = g1 ? v1 : (g2 ? v : v2);
      i2 = g1 ? i1 : (g2 ? ge : i2);
      v1 = g1 ? v : v1;
      i1 = g1 ? ge : i1;
    }
    S *= __expf(m_prev - v1);  // rescale old sum (chunk 0: 0*0=0)
#pragma unroll
    for (int e = 0; e < ECH; ++e) S += __expf(zc[e] - v1);
  }

  const float pa = 1.0f / S;             // p_soft[top1] (exp(0)=1)
  const float pb = __expf(v2 - v1) / S;  // p_soft[top2]
  const float d  = pa + pb + 1e-9f;      // ref renorm formula
  const float oa = av ? pa / d : 0.0f;
  const float ob = av ? pb / d : 0.0f;

  // ---- output: padded LDS transpose -> full 64B-line float4 stores ----
  const long obase = (long)blockIdx.x * BLOCK;
#pragma unroll 1
  for (int c = 0; c < NE / ECH; ++c) {
    __syncthreads();  // previous chunk's readers done before overwrite
#pragma unroll
    for (int e = 0; e < ECH; ++e) {
      const int ge = c * ECH + e;
      obuf[tid][e] = (ge == i1) ? oa : ((ge == i2) ? ob : 0.0f);
    }
    __syncthreads();
#pragma unroll
    for (int m = 0; m < 4; ++m) {
      const int f = m * BLOCK + tid;  // consecutive lanes -> consecutive 16B
      const int tok = f >> 2, part = f & 3;
      if (obase + tok < n) {
        const float4 v = *reinterpret_cast<const float4*>(&obuf[tok][part * 4]);
        reinterpret_cast<float4*>(out + (obase + tok) * (long)NE + c * ECH)[part] = v;
      }
    }
  }
}

extern "C" void kernel_launch(void* const* d_in, const int* in_sizes, int n_in,
                              void* d_out, int out_size, void* d_ws, size_t ws_size,
                              hipStream_t stream) {
  const float* x  = (const float*)d_in[0];
  const float* W1 = (const float*)d_in[1];
  const float* b1 = (const float*)d_in[2];
  const float* W2 = (const float*)d_in[3];
  const float* b2 = (const float*)d_in[4];
  float* out = (float*)d_out;
  const int n_tokens = in_sizes[0] / DIM_IN;
  const int grid = (n_tokens + BLOCK - 1) / BLOCK;
  hipLaunchKernelGGL(router_fwd, dim3(grid), dim3(BLOCK), 0, stream,
                     x, W1, b1, W2, b2, out, n_tokens);
}

// Round 7
// 459.286 us; speedup vs baseline: 22.2176x; 22.2176x over previous
//
#include <hip/hip_runtime.h>
#include <cfloat>

#define DIM_IN 256
#define HIDDEN 32
#define NE 64
#define ECH 16
#define BLOCK 256

// One token per thread. Round-3 structure (proven VGPR 84, no spill) with one
// change: layer-1 consumes 16-row groups (64B of x) and prefetches the NEXT
// group's four float4s before computing the current group from registers.
// 16 rows x 32 h-cols = 512 wave-FMAs (~1024 cy) > ~900 cy HBM latency, so
// the x stream stays hidden inside a single wave. Straight-line code only:
// no lambdas, no rotating buffers (rounds 5/6 showed those spill to scratch).
// Weights are read with wave-uniform indices -> s_load on the scalar pipe.
__launch_bounds__(BLOCK, 4)
__global__ void router_fwd(const float* __restrict__ x,
                           const float* __restrict__ W1,
                           const float* __restrict__ b1,
                           const float* __restrict__ W2,
                           const float* __restrict__ b2,
                           float* __restrict__ out, int n) {
  __shared__ float obuf[BLOCK][ECH + 1];  // +1 pad
  const int tid = threadIdx.x;
  const long t = (long)blockIdx.x * BLOCK + tid;
  const bool av = t < n;

  const float4* __restrict__ xr =
      reinterpret_cast<const float4*>(x + (av ? t : 0) * DIM_IN);

  float h[HIDDEN];
#pragma unroll
  for (int j = 0; j < HIDDEN; ++j) h[j] = 0.0f;

  // ---- layer 1: h = x @ W1, 16 rows/group, prefetch next group ----
  float4 c0 = xr[0], c1 = xr[1], c2 = xr[2], c3 = xr[3];

#pragma unroll 1
  for (int g = 0; g < 16; ++g) {
    const int nb = (g < 15 ? g + 1 : 15) * 4;  // g=15: reload (L1-hot, unused)
    const float4 n0 = xr[nb + 0];
    const float4 n1 = xr[nb + 1];
    const float4 n2 = xr[nb + 2];
    const float4 n3 = xr[nb + 3];
    const float xs[16] = {c0.x, c0.y, c0.z, c0.w, c1.x, c1.y, c1.z, c1.w,
                          c2.x, c2.y, c2.z, c2.w, c3.x, c3.y, c3.z, c3.w};
    const float* __restrict__ wbase = W1 + g * 16 * HIDDEN;  // uniform -> s_load
#pragma unroll
    for (int k = 0; k < 16; ++k) {
      const float xv = xs[k];
      const float* __restrict__ wrow = wbase + k * HIDDEN;
#pragma unroll
      for (int j = 0; j < HIDDEN; ++j) h[j] = fmaf(xv, wrow[j], h[j]);
    }
    c0 = n0; c1 = n1; c2 = n2; c3 = n3;
  }

  // bias + tanh.  tanh(v) = 1 - 2/(e^{2v}+1): no inf/inf NaN.
#pragma unroll
  for (int j = 0; j < HIDDEN; ++j) {
    const float v = h[j] + b1[j];
    const float e = __expf(2.0f * v);
    h[j] = 1.0f - 2.0f / (e + 1.0f);
  }

  // ---- layer 2 in 16-expert chunks + online top-2 / exp-sum ----
  float v1 = -FLT_MAX, v2 = -FLT_MAX, S = 0.0f;
  int i1 = 0, i2 = 0;

#pragma unroll 1
  for (int c = 0; c < NE / ECH; ++c) {
    float zc[ECH];
#pragma unroll
    for (int e = 0; e < ECH; ++e) zc[e] = 0.0f;
#pragma unroll
    for (int j = 0; j < HIDDEN; ++j) {
      const float hv = h[j];
      const float* __restrict__ wrow = W2 + j * NE + c * ECH;  // uniform
#pragma unroll
      for (int e = 0; e < ECH; ++e) zc[e] = fmaf(hv, wrow[e], zc[e]);
    }
    const float m_prev = v1;
    // strict '>' ascending scan => ties pick lower index (lax.top_k)
#pragma unroll
    for (int e = 0; e < ECH; ++e) {
      const float v = (zc[e] + b2[c * ECH + e]) * 10.0f;  // /TEMP
      zc[e] = v;
      const int ge = c * ECH + e;
      const bool g1 = v > v1;
      const bool g2 = v > v2;
      v2 = g1 ? v1 : (g2 ? v : v2);
      i2 = g1 ? i1 : (g2 ? ge : i2);
      v1 = g1 ? v : v1;
      i1 = g1 ? ge : i1;
    }
    S *= __expf(m_prev - v1);  // rescale old sum (chunk 0: 0*0=0)
#pragma unroll
    for (int e = 0; e < ECH; ++e) S += __expf(zc[e] - v1);
  }

  const float pa = 1.0f / S;             // p_soft[top1] (exp(0)=1)
  const float pb = __expf(v2 - v1) / S;  // p_soft[top2]
  const float d  = pa + pb + 1e-9f;      // ref renorm formula
  const float oa = av ? pa / d : 0.0f;
  const float ob = av ? pb / d : 0.0f;

  // ---- output: LDS transpose -> full 64B-line float4 stores ----
  const long obase = (long)blockIdx.x * BLOCK;
#pragma unroll 1
  for (int c = 0; c < NE / ECH; ++c) {
    __syncthreads();  // previous chunk's readers done before overwrite
#pragma unroll
    for (int e = 0; e < ECH; ++e) {
      const int ge = c * ECH + e;
      obuf[tid][e] = (ge == i1) ? oa : ((ge == i2) ? ob : 0.0f);
    }
    __syncthreads();
#pragma unroll
    for (int m = 0; m < 4; ++m) {
      const int f = m * BLOCK + tid;  // consecutive lanes -> consecutive 16B
      const int tok = f >> 2, part = f & 3;
      if (obase + tok < n) {
        float4 v;
        v.x = obuf[tok][part * 4 + 0];
        v.y = obuf[tok][part * 4 + 1];
        v.z = obuf[tok][part * 4 + 2];
        v.w = obuf[tok][part * 4 + 3];
        reinterpret_cast<float4*>(out + (obase + tok) * (long)NE + c * ECH)[part] = v;
      }
    }
  }
}

extern "C" void kernel_launch(void* const* d_in, const int* in_sizes, int n_in,
                              void* d_out, int out_size, void* d_ws, size_t ws_size,
                              hipStream_t stream) {
  const float* x  = (const float*)d_in[0];
  const float* W1 = (const float*)d_in[1];
  const float* b1 = (const float*)d_in[2];
  const float* W2 = (const float*)d_in[3];
  const float* b2 = (const float*)d_in[4];
  float* out = (float*)d_out;
  const int n_tokens = in_sizes[0] / DIM_IN;
  const int grid = (n_tokens + BLOCK - 1) / BLOCK;
  hipLaunchKernelGGL(router_fwd, dim3(grid), dim3(BLOCK), 0, stream,
                     x, W1, b1, W2, b2, out, n_tokens);
}